// Round 8
// baseline (751.488 us; speedup 1.0000x reference)
//
#include <hip/hip_runtime.h>
#include <hip/hip_bf16.h>

#define NND 30000
#define NE  480000
#define FD  256
#define HD  32
#define HEADS 4
#define NLAB 6
#define NEG_SLOPE 0.2f
#define BN_EPS 1e-5f

// ---- workspace layout (offsets in 4-byte elements) ----
#define WS_FLAG      0
#define WS_BNSUM     4
#define WS_BNSQ      260
#define WS_LOSS      516
#define WS_COUNTS    520
#define WS_ZERO_ELEMS 30524
#define WS_OFFSETS   30524
#define WS_CURSOR    60528
#define WS_GAMMA     90528
#define WS_BETA      90784
#define WS_WLIN      91040
#define WS_BLIN      123808
#define WS_WGAT      123936
#define WS_ATT       156704
#define WS_BGAT      156960
#define WS_WP        157088
#define WS_BP        157600
#define WS_RW        157616
#define WS_SCALE     182192
#define WS_SHIFT     182448
#define WS_WC        182704
#define WS_BC        248240
#define WS_SD        248496
#define WS_SS        368496
#define WS_ONORM     488496
#define WS_CSR       668496
#define WS_XF        1178496
// U reuses the XF region (XF dead after k_gemm; U written after k_aggr)
#define WS_U         1178496
#define WS_BLKSUM    5018496
#define WS_BLKOFF    5018624
// transposed weights OVERLAY the SD region (dead after k_aggr; k_prep runs after k_aggr)
#define WS_RWT       248496
#define WS_WPT       273072
#define WS_Y         8858496
#define WS_XCG       16538496

#define OUT_LOSS_IDX 180000
#define OUT_FEAT_IDX 180001

#define SCAN_NB 118   // ceil(30000/256)

__device__ __forceinline__ float lrelu(float a) { return a >= 0.0f ? a : NEG_SLOPE * a; }

__device__ __forceinline__ int dtype_flag(const unsigned int* gamma_raw) {
    return ((gamma_raw[0] & 0xFFFFu) == 0x3F80u) ? 1 : 0;  // bf16 pair vs f32 1.0
}

// ---- cross-lane helpers: DPP (VALU) for quad ops, immediate ds_swizzle for xor4/8/16 ----
template<int CTRL>
__device__ __forceinline__ float fdpp(float v) {
    return __int_as_float(__builtin_amdgcn_mov_dpp(__float_as_int(v), CTRL, 0xF, 0xF, true));
}
template<int PAT>
__device__ __forceinline__ float fswz(float v) {
    return __int_as_float(__builtin_amdgcn_ds_swizzle(__float_as_int(v), PAT));
}
// full reduce-broadcast over the lane's 32-lane group
__device__ __forceinline__ float redq(float v) {
    v += fdpp<0xB1>(v);        // xor 1
    v += fdpp<0x4E>(v);        // xor 2
    v += fswz<0x101F>(v);      // xor 4
    v += fswz<0x201F>(v);      // xor 8
    v += fswz<0x401F>(v);      // xor 16
    return v;
}
// lockstep 2-chain version — interleaves two independent reductions to hide latency
__device__ __forceinline__ void redq2(float& x, float& y) {
    { float a = fdpp<0xB1>(x),   b = fdpp<0xB1>(y);   x += a; y += b; }
    { float a = fdpp<0x4E>(x),   b = fdpp<0x4E>(y);   x += a; y += b; }
    { float a = fswz<0x101F>(x), b = fswz<0x101F>(y); x += a; y += b; }
    { float a = fswz<0x201F>(x), b = fswz<0x201F>(y); x += a; y += b; }
    { float a = fswz<0x401F>(x), b = fswz<0x401F>(y); x += a; y += b; }
}
__device__ __forceinline__ float redq_sum64(float v) {
    v = redq(v);
    return v + __shfl_xor(v, 32);
}
__device__ __forceinline__ float redq_max64(float v) {
    v = fmaxf(v, fdpp<0xB1>(v));
    v = fmaxf(v, fdpp<0x4E>(v));
    v = fmaxf(v, fswz<0x101F>(v));
    v = fmaxf(v, fswz<0x201F>(v));
    v = fmaxf(v, fswz<0x401F>(v));
    return fmaxf(v, __shfl_xor(v, 32));
}
__device__ __forceinline__ float sel4(const float d[8], int k, int base) {
    return (k == 0) ? d[base+0] : (k == 1) ? d[base+1] : (k == 2) ? d[base+2] : d[base+3];
}
// 8-value packed reduce over 32-lane group for TWO independent sets, lockstep
__device__ __forceinline__ void dreduce2(float d0[8], float d1[8], int k,
                                         float o0[8], float o1[8]) {
    #pragma unroll
    for (int j = 0; j < 8; ++j) {
        { float a = fdpp<0xB1>(d0[j]), b = fdpp<0xB1>(d1[j]); d0[j] += a; d1[j] += b; }
        { float a = fdpp<0x4E>(d0[j]), b = fdpp<0x4E>(d1[j]); d0[j] += a; d1[j] += b; }
    }
    float A0 = sel4(d0, k, 0), B0 = sel4(d0, k, 4);
    float A1 = sel4(d1, k, 0), B1 = sel4(d1, k, 4);
    { float a=fswz<0x101F>(A0), b=fswz<0x101F>(B0), c=fswz<0x101F>(A1), d=fswz<0x101F>(B1);
      A0+=a; B0+=b; A1+=c; B1+=d; }
    { float a=fswz<0x201F>(A0), b=fswz<0x201F>(B0), c=fswz<0x201F>(A1), d=fswz<0x201F>(B1);
      A0+=a; B0+=b; A1+=c; B1+=d; }
    { float a=fswz<0x401F>(A0), b=fswz<0x401F>(B0), c=fswz<0x401F>(A1), d=fswz<0x401F>(B1);
      A0+=a; B0+=b; A1+=c; B1+=d; }
    o0[0]=fdpp<0x00>(A0); o0[1]=fdpp<0x55>(A0); o0[2]=fdpp<0xAA>(A0); o0[3]=fdpp<0xFF>(A0);
    o0[4]=fdpp<0x00>(B0); o0[5]=fdpp<0x55>(B0); o0[6]=fdpp<0xAA>(B0); o0[7]=fdpp<0xFF>(B0);
    o1[0]=fdpp<0x00>(A1); o1[1]=fdpp<0x55>(A1); o1[2]=fdpp<0xAA>(A1); o1[3]=fdpp<0xFF>(A1);
    o1[4]=fdpp<0x00>(B1); o1[5]=fdpp<0x55>(B1); o1[6]=fdpp<0xAA>(B1); o1[7]=fdpp<0xFF>(B1);
}

__device__ __forceinline__ float cvt_load(const void* p, int i, int f) {
    if (f) return __bfloat162float(((const __hip_bfloat16*)p)[i]);
    return ((const float*)p)[i];
}

__global__ void k_convert(const void* src, float* dst, int n, const unsigned int* graw) {
    int f = dtype_flag(graw);
    for (int i = blockIdx.x * blockDim.x + threadIdx.x; i < n; i += gridDim.x * blockDim.x)
        dst[i] = cvt_load(src, i, f);
}

// all small float params packed into ws params block (p0 == gamma -> flag source)
__global__ void k_convert_params(const void* p0, const void* p1, const void* p2, const void* p3,
                                 const void* p4, const void* p5, const void* p6, const void* p7,
                                 const void* p8, const void* p9, float* dst) {
    int f = dtype_flag((const unsigned int*)p0);
    int i = blockIdx.x * blockDim.x + threadIdx.x;
    if (i >= 91664) return;
    const void* p; int off;
    if      (i < 256)   { p = p0; off = i; }
    else if (i < 512)   { p = p1; off = i - 256; }
    else if (i < 33280) { p = p2; off = i - 512; }
    else if (i < 33408) { p = p3; off = i - 33280; }
    else if (i < 66176) { p = p4; off = i - 33408; }
    else if (i < 66432) { p = p5; off = i - 66176; }
    else if (i < 66560) { p = p6; off = i - 66432; }
    else if (i < 67072) { p = p7; off = i - 66560; }
    else if (i < 67088) { p = p8; off = i - 67072; }
    else                { p = p9; off = i - 67088; }
    dst[i] = cvt_load(p, off, f);
}

// ---------- transpose weights for contiguous per-lane slices ----------
// runs AFTER k_aggr (rwT/wpT overlay the then-dead sD region)
__global__ void k_prep(const float* rwf, const float* Wpf, float* rwT, float* wpT) {
    int idx = blockIdx.x * blockDim.x + threadIdx.x;
    if (idx < 24576) {
        int i = idx & 7, r = (idx >> 3) & 15, o = (idx >> 7) & 31, c = idx >> 12;
        rwT[idx] = rwf[(((c * 16) + r) * 8 + i) * 32 + o];
    } else if (idx < 24576 + 512) {
        int f2 = idx - 24576;
        int k = f2 & 31, oo = (f2 >> 5) & 7, cc = f2 >> 8;
        wpT[f2] = Wpf[cc * 256 + k * 8 + oo];
    }
}

// ---------- batchnorm stats ----------
__global__ void k_bn_stats(const float* xf, float* bn_sum, float* bn_sq) {
    int t = threadIdx.x;
    int rows = (NND + gridDim.x - 1) / gridDim.x;
    int r0 = blockIdx.x * rows;
    int r1 = min(NND, r0 + rows);
    float s = 0.0f, ss = 0.0f;
    for (int r = r0; r < r1; ++r) {
        float v = xf[(size_t)r * FD + t];
        s += v; ss += v * v;
    }
    atomicAdd(&bn_sum[t], s);
    atomicAdd(&bn_sq[t], ss);
}

__global__ void k_bn_final(const float* bn_sum, const float* bn_sq, const float* gamma,
                           const float* beta, float* scale, float* shift) {
    int t = threadIdx.x;
    float mean = bn_sum[t] / (float)NND;
    float var  = bn_sq[t] / (float)NND - mean * mean;
    float inv  = 1.0f / sqrtf(var + BN_EPS);
    float sc   = gamma[t] * inv;
    scale[t] = sc;
    shift[t] = beta[t] - mean * sc;
}

// fold BN into combined weight Wc[k][j] (j<128: lin, j>=128: gat) and bias bc
__global__ void k_fold(const float* wlin, const float* wgat, const float* blin,
                       const float* scale, const float* shift, float* Wc, float* bc) {
    int j = blockIdx.x;
    int k = threadIdx.x;
    float w = (j < 128) ? wlin[k * 128 + j] : wgat[k * 128 + (j - 128)];
    Wc[k * 256 + j] = scale[k] * w;
    __shared__ float red[256];
    red[k] = shift[k] * w;
    __syncthreads();
    for (int s = 128; s > 0; s >>= 1) { if (k < s) red[k] += red[k + s]; __syncthreads(); }
    if (k == 0) bc[j] = red[0] + (j < 128 ? blin[j] : 0.0f);
}

// ---------- GEMM: Y[N][256] = xf[N][256] @ Wc[256][256] + bc ----------
__global__ __launch_bounds__(256) void k_gemm(const float* A, const float* B,
                                              const float* bias, float* C) {
    __shared__ __align__(16) float As[16][128];
    __shared__ __align__(16) float Bs[16][64];
    int t  = threadIdx.x;
    int bm = blockIdx.x * 128;
    int bn = blockIdx.y * 64;
    int tr = t / 16, tc = t % 16;
    float acc[8][4] = {};
    int alm = t >> 2;
    int alk = (t & 3) * 4;
    int blk = t >> 4;
    int bln = (t & 15) * 4;
    for (int k0 = 0; k0 < 256; k0 += 16) {
        #pragma unroll
        for (int half = 0; half < 2; ++half) {
            int row = bm + alm + half * 64;
            float4 av = make_float4(0.f, 0.f, 0.f, 0.f);
            if (row < NND) av = *(const float4*)(A + (size_t)row * 256 + k0 + alk);
            int m = alm + half * 64;
            As[alk + 0][m] = av.x; As[alk + 1][m] = av.y;
            As[alk + 2][m] = av.z; As[alk + 3][m] = av.w;
        }
        float4 bv = *(const float4*)(B + (size_t)(k0 + blk) * 256 + bn + bln);
        *(float4*)&Bs[blk][bln] = bv;
        __syncthreads();
        #pragma unroll
        for (int kk = 0; kk < 16; ++kk) {
            float a[8], b[4];
            *(float4*)&a[0] = *(const float4*)&As[kk][tr * 8];
            *(float4*)&a[4] = *(const float4*)&As[kk][tr * 8 + 4];
            *(float4*)&b[0] = *(const float4*)&Bs[kk][tc * 4];
            #pragma unroll
            for (int i = 0; i < 8; ++i)
                #pragma unroll
                for (int j = 0; j < 4; ++j) acc[i][j] += a[i] * b[j];
        }
        __syncthreads();
    }
    #pragma unroll
    for (int i = 0; i < 8; ++i) {
        int row = bm + tr * 8 + i;
        if (row < NND) {
            int col = bn + tc * 4;
            float4 o;
            o.x = acc[i][0] + bias[col + 0];
            o.y = acc[i][1] + bias[col + 1];
            o.z = acc[i][2] + bias[col + 2];
            o.w = acc[i][3] + bias[col + 3];
            *(float4*)(C + (size_t)row * 256 + col) = o;
        }
    }
}

// ---------- per-node attention scores ----------
__global__ void k_scores(const float* Y, const float* attf, float* sD, float* sS) {
    int idx = blockIdx.x * blockDim.x + threadIdx.x;
    if (idx >= NND * HEADS) return;
    int n = idx >> 2, h = idx & 3;
    const float* xrow = Y + (size_t)n * 256 + 128 + h * 32;
    const float* ai = attf + h * 64;
    const float* aj = ai + 32;
    float si = 0.f, sj = 0.f;
    #pragma unroll
    for (int k = 0; k < 32; ++k) { float v = xrow[k]; si += v * ai[k]; sj += v * aj[k]; }
    sD[idx] = si; sS[idx] = sj;
}

// ---------- CSR build ----------
__global__ void k_count(const int* ei, int* counts) {
    int e = blockIdx.x * blockDim.x + threadIdx.x;
    if (e >= NE + NND) return;
    int d = (e < NE) ? ei[NE + e] : (e - NE);
    atomicAdd(&counts[d], 1);
}

__global__ void k_scan_blk(const int* counts, int* offsets, int* blksum) {
    int t = threadIdx.x, b = blockIdx.x;
    int i = b * 256 + t;
    int v = (i < NND) ? counts[i] : 0;
    int lane = t & 63, wv = t >> 6;
    int x = v;
    #pragma unroll
    for (int off = 1; off < 64; off <<= 1) {
        int y = __shfl_up(x, off);
        if (lane >= off) x += y;
    }
    __shared__ int wsum[4];
    if (lane == 63) wsum[wv] = x;
    __syncthreads();
    int add = 0;
    #pragma unroll
    for (int w = 0; w < 4; ++w) add += (w < wv) ? wsum[w] : 0;
    if (i < NND) offsets[i] = add + x - v;
    if (t == 255) blksum[b] = add + x;
}

__global__ void k_scan_top(const int* blksum, int* blkoff) {
    int t = threadIdx.x;
    int v = (t < SCAN_NB) ? blksum[t] : 0;
    int lane = t & 63, wv = t >> 6;
    int x = v;
    #pragma unroll
    for (int off = 1; off < 64; off <<= 1) {
        int y = __shfl_up(x, off);
        if (lane >= off) x += y;
    }
    __shared__ int ws2[2];
    if (lane == 63) ws2[wv] = x;
    __syncthreads();
    int add = (wv == 1) ? ws2[0] : 0;
    if (t < SCAN_NB) blkoff[t] = add + x - v;
}

__global__ void k_scan_add(const int* blkoff, int* offsets, int* cursor) {
    int i = blockIdx.x * 256 + threadIdx.x;
    if (i >= NND) return;
    int o = offsets[i] + blkoff[blockIdx.x];
    offsets[i] = o;
    cursor[i] = o;
}

__global__ void k_scatter(const int* ei, int* cursor, int* csr) {
    int e = blockIdx.x * blockDim.x + threadIdx.x;
    if (e >= NE + NND) return;
    int s, d;
    if (e < NE) { s = ei[e]; d = ei[NE + e]; } else { s = d = e - NE; }
    int pos = atomicAdd(&cursor[d], 1);
    csr[pos] = s;
}

// ---------- GAT aggregation: one wave per node ----------
__global__ __launch_bounds__(256) void k_aggr(const float* Y, const float* sD, const float* sS,
                                              const int* offsets, const int* counts, const int* csr,
                                              const float* bgat, float* xcg) {
    int wave = (blockIdx.x * blockDim.x + threadIdx.x) >> 6;
    int lane = threadIdx.x & 63;
    if (wave >= NND) return;
    int n = wave;
    int start = offsets[n], deg = counts[n];
    float4 sd = *(const float4*)(sD + (size_t)n * 4);
    float m0 = -1e30f, m1 = -1e30f, m2 = -1e30f, m3 = -1e30f;
    for (int e = lane; e < deg; e += 64) {
        int s = csr[start + e];
        float4 sj = *(const float4*)(sS + (size_t)s * 4);
        m0 = fmaxf(m0, lrelu(sd.x + sj.x));
        m1 = fmaxf(m1, lrelu(sd.y + sj.y));
        m2 = fmaxf(m2, lrelu(sd.z + sj.z));
        m3 = fmaxf(m3, lrelu(sd.w + sj.w));
    }
    m0 = redq_max64(m0); m1 = redq_max64(m1);
    m2 = redq_max64(m2); m3 = redq_max64(m3);
    float s0 = 0.f, s1 = 0.f, s2 = 0.f, s3 = 0.f;
    for (int e = lane; e < deg; e += 64) {
        int s = csr[start + e];
        float4 sj = *(const float4*)(sS + (size_t)s * 4);
        s0 += __expf(lrelu(sd.x + sj.x) - m0);
        s1 += __expf(lrelu(sd.y + sj.y) - m1);
        s2 += __expf(lrelu(sd.z + sj.z) - m2);
        s3 += __expf(lrelu(sd.w + sj.w) - m3);
    }
    s0 = redq_sum64(s0); s1 = redq_sum64(s1);
    s2 = redq_sum64(s2); s3 = redq_sum64(s3);
    float i0 = 1.0f / (s0 + 1e-16f), i1 = 1.0f / (s1 + 1e-16f);
    float i2 = 1.0f / (s2 + 1e-16f), i3 = 1.0f / (s3 + 1e-16f);
    float acc0 = 0.f, acc1 = 0.f;
    int hA = lane >> 5;
    for (int base = 0; base < deg; base += 64) {
        int cnt = min(64, deg - base);
        int sidx = 0; float w0 = 0.f, w1 = 0.f, w2 = 0.f, w3 = 0.f;
        if (base + lane < deg) {
            sidx = csr[start + base + lane];
            float4 sj = *(const float4*)(sS + (size_t)sidx * 4);
            w0 = __expf(lrelu(sd.x + sj.x) - m0) * i0;
            w1 = __expf(lrelu(sd.y + sj.y) - m1) * i1;
            w2 = __expf(lrelu(sd.z + sj.z) - m2) * i2;
            w3 = __expf(lrelu(sd.w + sj.w) - m3) * i3;
        }
        for (int j = 0; j < cnt; ++j) {
            int s2i = __builtin_amdgcn_readlane(sidx, j);
            float wa0 = __int_as_float(__builtin_amdgcn_readlane(__float_as_int(w0), j));
            float wa1 = __int_as_float(__builtin_amdgcn_readlane(__float_as_int(w1), j));
            float wb0 = __int_as_float(__builtin_amdgcn_readlane(__float_as_int(w2), j));
            float wb1 = __int_as_float(__builtin_amdgcn_readlane(__float_as_int(w3), j));
            float wA = hA ? wa1 : wa0;
            float wB = hA ? wb1 : wb0;
            const float* xrow = Y + (size_t)s2i * 256 + 128;
            acc0 += wA * xrow[lane];
            acc1 += wB * xrow[64 + lane];
        }
    }
    float r0 = acc0 + bgat[lane];
    float r1 = acc1 + bgat[64 + lane];
    xcg[(size_t)n * 128 + lane]      = r0 > 0.f ? r0 : 0.f;
    xcg[(size_t)n * 128 + 64 + lane] = r1 > 0.f ? r1 : 0.f;
}

// ---------- primary caps: u[n][128], one wave per node, barrier-free ----------
__global__ __launch_bounds__(256) void k_u(const float* Y, const float* xcg,
                                           const float* wpT, const float* bpf, float* uG) {
    int lane = threadIdx.x & 63;
    int gw = blockIdx.x * 4 + (threadIdx.x >> 6);
    int nwaves = gridDim.x * 4;
    int r = lane >> 3, oo = lane & 7;
    const float* wA = wpT + oo * 32;
    const float* wB = wpT + 256 + oo * 32;
    float bpA = bpf[oo], bpB = bpf[8 + oo];
    for (int n = gw; n < NND; n += nwaves) {
        const float* rowp = (r < 4) ? (xcg + (size_t)n * 128 + r * 32)
                                    : (Y + (size_t)n * 256 + (r - 4) * 32);
        float pcA = bpA, pcB = bpB;
        #pragma unroll
        for (int k4 = 0; k4 < 8; ++k4) {
            float4 xv = *(const float4*)(rowp + k4 * 4);
            float4 wa = *(const float4*)(wA + k4 * 4);
            float4 wb = *(const float4*)(wB + k4 * 4);
            xv.x = fmaxf(xv.x, 0.f); xv.y = fmaxf(xv.y, 0.f);
            xv.z = fmaxf(xv.z, 0.f); xv.w = fmaxf(xv.w, 0.f);
            pcA += xv.x * wa.x + xv.y * wa.y + xv.z * wa.z + xv.w * wa.w;
            pcB += xv.x * wb.x + xv.y * wb.y + xv.z * wb.z + xv.w * wb.w;
        }
        float sA = pcA * pcA, sB = pcB * pcB;
        sA += fdpp<0xB1>(sA); sA += fdpp<0x4E>(sA); sA += fswz<0x101F>(sA);
        sB += fdpp<0xB1>(sB); sB += fdpp<0x4E>(sB); sB += fswz<0x101F>(sB);
        float cA = sqrtf(sA) / (1.0f + sA);
        float cB = sqrtf(sB) / (1.0f + sB);
        uG[(size_t)n * 128 + lane]      = pcA * cA;
        uG[(size_t)n * 128 + 64 + lane] = pcB * cB;
    }
}

// ---------- dynamic routing: one wave per (node,c), 2-way node ILP ----------
// Each wave processes node pair (n, n+4096) per iteration; the two independent
// routing dependency chains are interleaved in lockstep (redq2/dreduce2) so
// cross-lane latency (~25cyc/swizzle) is shared. rw slice contiguous in rwT.
__global__ __launch_bounds__(256, 4) void k_route6(const float* uG, const float* rwT,
                                                   float* onorm, void* dout,
                                                   const unsigned int* graw) {
    int flag = dtype_flag(graw);
    int t = threadIdx.x;
    int lane = t & 63;
    int c = blockIdx.x >> 10;
    int chunk = blockIdx.x & 1023;
    int wv = t >> 6;
    int widx = chunk * 4 + wv;          // 0..4095
    const int nstep = 4096;
    int h = lane >> 5, o = lane & 31;
    int k = lane & 3;
    const float* rwp = rwT + ((size_t)(c * 32 + o) * 16 + h * 8) * 8;  // 64 contiguous floats
    float4 ra[8], rb[8];
    #pragma unroll
    for (int j = 0; j < 8; ++j) {
        ra[j] = *(const float4*)(rwp + j * 8);
        rb[j] = *(const float4*)(rwp + j * 8 + 4);
    }
    float* outf = (float*)dout;
    __hip_bfloat16* outb = (__hip_bfloat16*)dout;
    for (int n0 = widx; n0 < NND; n0 += 2 * nstep) {
        int n1 = n0 + nstep;
        bool ok1 = (n1 < NND);
        const float* up0 = uG + (size_t)n0 * 128 + h * 64;
        const float* up1 = uG + (size_t)(ok1 ? n1 : n0) * 128 + h * 64;
        float p0[8], p1[8];
        #pragma unroll
        for (int j = 0; j < 8; ++j) {
            float4 a0 = *(const float4*)(up0 + j * 8);
            float4 b0 = *(const float4*)(up0 + j * 8 + 4);
            float4 a1 = *(const float4*)(up1 + j * 8);
            float4 b1 = *(const float4*)(up1 + j * 8 + 4);
            p0[j] = a0.x*ra[j].x + a0.y*ra[j].y + a0.z*ra[j].z + a0.w*ra[j].w
                  + b0.x*rb[j].x + b0.y*rb[j].y + b0.z*rb[j].z + b0.w*rb[j].w;
            p1[j] = a1.x*ra[j].x + a1.y*ra[j].y + a1.z*ra[j].z + a1.w*ra[j].w
                  + b1.x*rb[j].x + b1.y*rb[j].y + b1.z*rb[j].z + b1.w*rb[j].w;
        }
        // ---- iter 1: probs = 1/16 exactly ----
        float tl0 = p0[0]+p0[1]+p0[2]+p0[3]+p0[4]+p0[5]+p0[6]+p0[7];
        float tl1 = p1[0]+p1[1]+p1[2]+p1[3]+p1[4]+p1[5]+p1[6]+p1[7];
        float x0 = __shfl_xor(tl0, 32);
        float x1 = __shfl_xor(tl1, 32);
        float s0 = (tl0 + x0) * 0.0625f;
        float s1 = (tl1 + x1) * 0.0625f;
        float sq0 = s0 * s0, sq1 = s1 * s1;
        redq2(sq0, sq1);
        float v0 = s0 * (sqrtf(sq0) / (1.0f + sq0));
        float v1 = s1 * (sqrtf(sq1) / (1.0f + sq1));
        float lg0[8], lg1[8], dp0[8], dp1[8];
        #pragma unroll
        for (int j = 0; j < 8; ++j) { dp0[j] = p0[j] * v0; dp1[j] = p1[j] * v1; }
        dreduce2(dp0, dp1, k, lg0, lg1);
        // ---- iters 2,3 ----
        float sq3_0 = 0.f, v3_0 = 0.f, sq3_1 = 0.f, v3_1 = 0.f;
        #pragma unroll
        for (int it = 0; it < 2; ++it) {
            float mx0 = lg0[0], mx1 = lg1[0];
            #pragma unroll
            for (int j = 1; j < 8; ++j) { mx0 = fmaxf(mx0, lg0[j]); mx1 = fmaxf(mx1, lg1[j]); }
            float mm0 = __shfl_xor(mx0, 32);
            float mm1 = __shfl_xor(mx1, 32);
            mx0 = fmaxf(mx0, mm0); mx1 = fmaxf(mx1, mm1);
            float e0[8], e1[8]; float se0 = 0.f, se1 = 0.f;
            #pragma unroll
            for (int j = 0; j < 8; ++j) {
                e0[j] = __expf(lg0[j] - mx0); se0 += e0[j];
                e1[j] = __expf(lg1[j] - mx1); se1 += e1[j];
            }
            float so0 = __shfl_xor(se0, 32);
            float so1 = __shfl_xor(se1, 32);
            se0 += so0; se1 += so1;
            float inv0 = 1.0f / se0, inv1 = 1.0f / se1;
            float sl0 = 0.f, sl1 = 0.f;
            #pragma unroll
            for (int j = 0; j < 8; ++j) { sl0 += e0[j] * p0[j]; sl1 += e1[j] * p1[j]; }
            sl0 *= inv0; sl1 *= inv1;
            float c0 = __shfl_xor(sl0, 32);
            float c1 = __shfl_xor(sl1, 32);
            float ss0 = sl0 + c0, ss1 = sl1 + c1;
            float q0 = ss0 * ss0, q1 = ss1 * ss1;
            redq2(q0, q1);
            float vv0 = ss0 * (sqrtf(q0) / (1.0f + q0));
            float vv1 = ss1 * (sqrtf(q1) / (1.0f + q1));
            if (it == 0) {
                float dd0[8], dd1[8], lu0[8], lu1[8];
                #pragma unroll
                for (int j = 0; j < 8; ++j) { dd0[j] = p0[j] * vv0; dd1[j] = p1[j] * vv1; }
                dreduce2(dd0, dd1, k, lu0, lu1);
                #pragma unroll
                for (int j = 0; j < 8; ++j) { lg0[j] += lu0[j]; lg1[j] += lu1[j]; }
            } else { v3_0 = vv0; sq3_0 = q0; v3_1 = vv1; sq3_1 = q1; }
        }
        // ---- output ----
        if (lane < 32) {
            size_t f0 = (size_t)OUT_FEAT_IDX + (size_t)n0 * 192 + c * 32 + o;
            if (flag) outb[f0] = __float2bfloat16(v3_0); else outf[f0] = v3_0;
            if (ok1) {
                size_t f1 = (size_t)OUT_FEAT_IDX + (size_t)n1 * 192 + c * 32 + o;
                if (flag) outb[f1] = __float2bfloat16(v3_1); else outf[f1] = v3_1;
            }
            if (lane == 0) {
                float norm0 = sq3_0 / (1.0f + sq3_0);
                onorm[n0 * 6 + c] = norm0;
                size_t o0i = (size_t)n0 * 6 + c;
                if (flag) outb[o0i] = __float2bfloat16(norm0); else outf[o0i] = norm0;
                if (ok1) {
                    float norm1 = sq3_1 / (1.0f + sq3_1);
                    onorm[n1 * 6 + c] = norm1;
                    size_t o1i = (size_t)n1 * 6 + c;
                    if (flag) outb[o1i] = __float2bfloat16(norm1); else outf[o1i] = norm1;
                }
            }
        }
    }
}

// ---------- loss ----------
__global__ void k_loss(const float* onorm, const int* y, float* acc) {
    float l = 0.f;
    for (int n = blockIdx.x * blockDim.x + threadIdx.x; n < NND; n += gridDim.x * blockDim.x) {
        const float* v = onorm + n * 6;
        float m = v[0];
        #pragma unroll
        for (int cc = 1; cc < 6; ++cc) m = fmaxf(m, v[cc]);
        float s = 0.f;
        #pragma unroll
        for (int cc = 0; cc < 6; ++cc) s += expf(v[cc] - m);
        l += m + logf(s) - v[y[n]];
    }
    __shared__ float red[256];
    red[threadIdx.x] = l;
    __syncthreads();
    for (int s = 128; s > 0; s >>= 1) { if (threadIdx.x < s) red[threadIdx.x] += red[threadIdx.x + s]; __syncthreads(); }
    if (threadIdx.x == 0) atomicAdd(acc, red[0]);
}

__global__ void k_loss_fin(const float* acc, void* dout, const unsigned int* graw) {
    float v = acc[0] / (float)NND;
    if (dtype_flag(graw)) ((__hip_bfloat16*)dout)[OUT_LOSS_IDX] = __float2bfloat16(v);
    else                  ((float*)dout)[OUT_LOSS_IDX] = v;
}

extern "C" void kernel_launch(void* const* d_in, const int* in_sizes, int n_in,
                              void* d_out, int out_size, void* d_ws, size_t ws_size,
                              hipStream_t stream) {
    (void)in_sizes; (void)n_in; (void)out_size; (void)ws_size;
    float* ws = (float*)d_ws;
    int*  wsi = (int*)d_ws;
    const int* ei = (const int*)d_in[11];
    const int* y  = (const int*)d_in[12];
    const unsigned int* graw = (const unsigned int*)d_in[1];

    hipMemsetAsync(d_ws, 0, (size_t)WS_ZERO_ELEMS * 4, stream);

    k_convert<<<2048, 256, 0, stream>>>(d_in[0], ws + WS_XF, NND * FD, graw);
    k_convert_params<<<(91664 + 255) / 256, 256, 0, stream>>>(
        d_in[1], d_in[2], d_in[3], d_in[4], d_in[5], d_in[6], d_in[7], d_in[8], d_in[9], d_in[10],
        ws + WS_GAMMA);

    k_bn_stats<<<120, 256, 0, stream>>>(ws + WS_XF, ws + WS_BNSUM, ws + WS_BNSQ);
    k_bn_final<<<1, 256, 0, stream>>>(ws + WS_BNSUM, ws + WS_BNSQ, ws + WS_GAMMA, ws + WS_BETA,
                                      ws + WS_SCALE, ws + WS_SHIFT);
    k_fold<<<256, 256, 0, stream>>>(ws + WS_WLIN, ws + WS_WGAT, ws + WS_BLIN,
                                    ws + WS_SCALE, ws + WS_SHIFT, ws + WS_WC, ws + WS_BC);

    k_gemm<<<dim3((NND + 127) / 128, 4), 256, 0, stream>>>(ws + WS_XF, ws + WS_WC, ws + WS_BC, ws + WS_Y);

    k_scores<<<(NND * HEADS + 255) / 256, 256, 0, stream>>>(ws + WS_Y, ws + WS_ATT, ws + WS_SD, ws + WS_SS);

    k_count<<<(NE + NND + 255) / 256, 256, 0, stream>>>(ei, wsi + WS_COUNTS);
    k_scan_blk<<<SCAN_NB, 256, 0, stream>>>(wsi + WS_COUNTS, wsi + WS_OFFSETS, wsi + WS_BLKSUM);
    k_scan_top<<<1, 128, 0, stream>>>(wsi + WS_BLKSUM, wsi + WS_BLKOFF);
    k_scan_add<<<SCAN_NB, 256, 0, stream>>>(wsi + WS_BLKOFF, wsi + WS_OFFSETS, wsi + WS_CURSOR);
    k_scatter<<<(NE + NND + 255) / 256, 256, 0, stream>>>(ei, wsi + WS_CURSOR, wsi + WS_CSR);

    k_aggr<<<(NND + 3) / 4, 256, 0, stream>>>(ws + WS_Y, ws + WS_SD, ws + WS_SS,
                                              wsi + WS_OFFSETS, wsi + WS_COUNTS, wsi + WS_CSR,
                                              ws + WS_BGAT, ws + WS_XCG);

    // rwT/wpT overlay the sD region — safe only after k_aggr's last read of sD
    k_prep<<<(24576 + 512 + 255) / 256, 256, 0, stream>>>(ws + WS_RW, ws + WS_WP,
                                                          ws + WS_RWT, ws + WS_WPT);

    k_u<<<512, 256, 0, stream>>>(ws + WS_Y, ws + WS_XCG, ws + WS_WPT, ws + WS_BP, ws + WS_U);
    k_route6<<<6144, 256, 0, stream>>>(ws + WS_U, ws + WS_RWT, ws + WS_ONORM, d_out, graw);

    k_loss<<<118, 256, 0, stream>>>(ws + WS_ONORM, y, ws + WS_LOSS);
    k_loss_fin<<<1, 1, 0, stream>>>(ws + WS_LOSS, d_out, graw);
}

// Round 9
// 647.832 us; speedup vs baseline: 1.1600x; 1.1600x over previous
//
#include <hip/hip_runtime.h>
#include <hip/hip_bf16.h>

#define NND 30000
#define NE  480000
#define FD  256
#define HD  32
#define HEADS 4
#define NLAB 6
#define NEG_SLOPE 0.2f
#define BN_EPS 1e-5f

// ---- workspace layout (offsets in 4-byte elements) ----
#define WS_FLAG      0
#define WS_BNSUM     4
#define WS_BNSQ      260
#define WS_LOSS      516
#define WS_COUNTS    520
#define WS_ZERO_ELEMS 30524
#define WS_OFFSETS   30524
#define WS_CURSOR    60528
#define WS_GAMMA     90528
#define WS_BETA      90784
#define WS_WLIN      91040
#define WS_BLIN      123808
#define WS_WGAT      123936
#define WS_ATT       156704
#define WS_BGAT      156960
#define WS_WP        157088
#define WS_BP        157600
#define WS_RW        157616
#define WS_SCALE     182192
#define WS_SHIFT     182448
#define WS_WC        182704
#define WS_BC        248240
#define WS_SD        248496
#define WS_SS        368496
#define WS_ONORM     488496
#define WS_CSR       668496
#define WS_XF        1178496
// U reuses the XF region (XF dead after k_gemm; U written after k_aggr)
#define WS_U         1178496
#define WS_BLKSUM    5018496
#define WS_BLKOFF    5018624
// transposed weights OVERLAY the SD region (dead after k_aggr; k_prep runs after k_aggr)
#define WS_RWT       248496
#define WS_WPT       273072
#define WS_Y         8858496
#define WS_XCG       16538496

#define OUT_LOSS_IDX 180000
#define OUT_FEAT_IDX 180001

#define SCAN_NB 118   // ceil(30000/256)

__device__ __forceinline__ float lrelu(float a) { return a >= 0.0f ? a : NEG_SLOPE * a; }

__device__ __forceinline__ int dtype_flag(const unsigned int* gamma_raw) {
    return ((gamma_raw[0] & 0xFFFFu) == 0x3F80u) ? 1 : 0;  // bf16 pair vs f32 1.0
}

// ---- cross-lane helpers: DPP (VALU) for quad ops, immediate ds_swizzle for xor4/8/16 ----
template<int CTRL>
__device__ __forceinline__ float fdpp(float v) {
    return __int_as_float(__builtin_amdgcn_mov_dpp(__float_as_int(v), CTRL, 0xF, 0xF, true));
}
template<int PAT>
__device__ __forceinline__ float fswz(float v) {
    return __int_as_float(__builtin_amdgcn_ds_swizzle(__float_as_int(v), PAT));
}
// full reduce-broadcast over the lane's 32-lane group
__device__ __forceinline__ float redq(float v) {
    v += fdpp<0xB1>(v);        // xor 1
    v += fdpp<0x4E>(v);        // xor 2
    v += fswz<0x101F>(v);      // xor 4
    v += fswz<0x201F>(v);      // xor 8
    v += fswz<0x401F>(v);      // xor 16
    return v;
}
// lockstep 2-chain version — interleaves two independent reductions to hide latency
__device__ __forceinline__ void redq2(float& x, float& y) {
    { float a = fdpp<0xB1>(x),   b = fdpp<0xB1>(y);   x += a; y += b; }
    { float a = fdpp<0x4E>(x),   b = fdpp<0x4E>(y);   x += a; y += b; }
    { float a = fswz<0x101F>(x), b = fswz<0x101F>(y); x += a; y += b; }
    { float a = fswz<0x201F>(x), b = fswz<0x201F>(y); x += a; y += b; }
    { float a = fswz<0x401F>(x), b = fswz<0x401F>(y); x += a; y += b; }
}
__device__ __forceinline__ float redq_sum64(float v) {
    v = redq(v);
    return v + __shfl_xor(v, 32);
}
__device__ __forceinline__ float redq_max64(float v) {
    v = fmaxf(v, fdpp<0xB1>(v));
    v = fmaxf(v, fdpp<0x4E>(v));
    v = fmaxf(v, fswz<0x101F>(v));
    v = fmaxf(v, fswz<0x201F>(v));
    v = fmaxf(v, fswz<0x401F>(v));
    return fmaxf(v, __shfl_xor(v, 32));
}
__device__ __forceinline__ float sel4(const float d[8], int k, int base) {
    return (k == 0) ? d[base+0] : (k == 1) ? d[base+1] : (k == 2) ? d[base+2] : d[base+3];
}
// 8-value packed reduce over 32-lane group for TWO independent sets, lockstep
__device__ __forceinline__ void dreduce2(float d0[8], float d1[8], int k,
                                         float o0[8], float o1[8]) {
    #pragma unroll
    for (int j = 0; j < 8; ++j) {
        { float a = fdpp<0xB1>(d0[j]), b = fdpp<0xB1>(d1[j]); d0[j] += a; d1[j] += b; }
        { float a = fdpp<0x4E>(d0[j]), b = fdpp<0x4E>(d1[j]); d0[j] += a; d1[j] += b; }
    }
    float A0 = sel4(d0, k, 0), B0 = sel4(d0, k, 4);
    float A1 = sel4(d1, k, 0), B1 = sel4(d1, k, 4);
    { float a=fswz<0x101F>(A0), b=fswz<0x101F>(B0), c=fswz<0x101F>(A1), d=fswz<0x101F>(B1);
      A0+=a; B0+=b; A1+=c; B1+=d; }
    { float a=fswz<0x201F>(A0), b=fswz<0x201F>(B0), c=fswz<0x201F>(A1), d=fswz<0x201F>(B1);
      A0+=a; B0+=b; A1+=c; B1+=d; }
    { float a=fswz<0x401F>(A0), b=fswz<0x401F>(B0), c=fswz<0x401F>(A1), d=fswz<0x401F>(B1);
      A0+=a; B0+=b; A1+=c; B1+=d; }
    o0[0]=fdpp<0x00>(A0); o0[1]=fdpp<0x55>(A0); o0[2]=fdpp<0xAA>(A0); o0[3]=fdpp<0xFF>(A0);
    o0[4]=fdpp<0x00>(B0); o0[5]=fdpp<0x55>(B0); o0[6]=fdpp<0xAA>(B0); o0[7]=fdpp<0xFF>(B0);
    o1[0]=fdpp<0x00>(A1); o1[1]=fdpp<0x55>(A1); o1[2]=fdpp<0xAA>(A1); o1[3]=fdpp<0xFF>(A1);
    o1[4]=fdpp<0x00>(B1); o1[5]=fdpp<0x55>(B1); o1[6]=fdpp<0xAA>(B1); o1[7]=fdpp<0xFF>(B1);
}

__device__ __forceinline__ float cvt_load(const void* p, int i, int f) {
    if (f) return __bfloat162float(((const __hip_bfloat16*)p)[i]);
    return ((const float*)p)[i];
}

__global__ void k_convert(const void* src, float* dst, int n, const unsigned int* graw) {
    int f = dtype_flag(graw);
    for (int i = blockIdx.x * blockDim.x + threadIdx.x; i < n; i += gridDim.x * blockDim.x)
        dst[i] = cvt_load(src, i, f);
}

// all small float params packed into ws params block (p0 == gamma -> flag source)
__global__ void k_convert_params(const void* p0, const void* p1, const void* p2, const void* p3,
                                 const void* p4, const void* p5, const void* p6, const void* p7,
                                 const void* p8, const void* p9, float* dst) {
    int f = dtype_flag((const unsigned int*)p0);
    int i = blockIdx.x * blockDim.x + threadIdx.x;
    if (i >= 91664) return;
    const void* p; int off;
    if      (i < 256)   { p = p0; off = i; }
    else if (i < 512)   { p = p1; off = i - 256; }
    else if (i < 33280) { p = p2; off = i - 512; }
    else if (i < 33408) { p = p3; off = i - 33280; }
    else if (i < 66176) { p = p4; off = i - 33408; }
    else if (i < 66432) { p = p5; off = i - 66176; }
    else if (i < 66560) { p = p6; off = i - 66432; }
    else if (i < 67072) { p = p7; off = i - 66560; }
    else if (i < 67088) { p = p8; off = i - 67072; }
    else                { p = p9; off = i - 67088; }
    dst[i] = cvt_load(p, off, f);
}

// ---------- transpose weights for contiguous per-lane slices ----------
// runs AFTER k_aggr (rwT/wpT overlay the then-dead sD region)
__global__ void k_prep(const float* rwf, const float* Wpf, float* rwT, float* wpT) {
    int idx = blockIdx.x * blockDim.x + threadIdx.x;
    if (idx < 24576) {
        int i = idx & 7, r = (idx >> 3) & 15, o = (idx >> 7) & 31, c = idx >> 12;
        rwT[idx] = rwf[(((c * 16) + r) * 8 + i) * 32 + o];
    } else if (idx < 24576 + 512) {
        int f2 = idx - 24576;
        int k = f2 & 31, oo = (f2 >> 5) & 7, cc = f2 >> 8;
        wpT[f2] = Wpf[cc * 256 + k * 8 + oo];
    }
}

// ---------- batchnorm stats ----------
__global__ void k_bn_stats(const float* xf, float* bn_sum, float* bn_sq) {
    int t = threadIdx.x;
    int rows = (NND + gridDim.x - 1) / gridDim.x;
    int r0 = blockIdx.x * rows;
    int r1 = min(NND, r0 + rows);
    float s = 0.0f, ss = 0.0f;
    for (int r = r0; r < r1; ++r) {
        float v = xf[(size_t)r * FD + t];
        s += v; ss += v * v;
    }
    atomicAdd(&bn_sum[t], s);
    atomicAdd(&bn_sq[t], ss);
}

__global__ void k_bn_final(const float* bn_sum, const float* bn_sq, const float* gamma,
                           const float* beta, float* scale, float* shift) {
    int t = threadIdx.x;
    float mean = bn_sum[t] / (float)NND;
    float var  = bn_sq[t] / (float)NND - mean * mean;
    float inv  = 1.0f / sqrtf(var + BN_EPS);
    float sc   = gamma[t] * inv;
    scale[t] = sc;
    shift[t] = beta[t] - mean * sc;
}

// fold BN into combined weight Wc[k][j] (j<128: lin, j>=128: gat) and bias bc
__global__ void k_fold(const float* wlin, const float* wgat, const float* blin,
                       const float* scale, const float* shift, float* Wc, float* bc) {
    int j = blockIdx.x;
    int k = threadIdx.x;
    float w = (j < 128) ? wlin[k * 128 + j] : wgat[k * 128 + (j - 128)];
    Wc[k * 256 + j] = scale[k] * w;
    __shared__ float red[256];
    red[k] = shift[k] * w;
    __syncthreads();
    for (int s = 128; s > 0; s >>= 1) { if (k < s) red[k] += red[k + s]; __syncthreads(); }
    if (k == 0) bc[j] = red[0] + (j < 128 ? blin[j] : 0.0f);
}

// ---------- GEMM: Y[N][256] = xf[N][256] @ Wc[256][256] + bc ----------
__global__ __launch_bounds__(256) void k_gemm(const float* A, const float* B,
                                              const float* bias, float* C) {
    __shared__ __align__(16) float As[16][128];
    __shared__ __align__(16) float Bs[16][64];
    int t  = threadIdx.x;
    int bm = blockIdx.x * 128;
    int bn = blockIdx.y * 64;
    int tr = t / 16, tc = t % 16;
    float acc[8][4] = {};
    int alm = t >> 2;
    int alk = (t & 3) * 4;
    int blk = t >> 4;
    int bln = (t & 15) * 4;
    for (int k0 = 0; k0 < 256; k0 += 16) {
        #pragma unroll
        for (int half = 0; half < 2; ++half) {
            int row = bm + alm + half * 64;
            float4 av = make_float4(0.f, 0.f, 0.f, 0.f);
            if (row < NND) av = *(const float4*)(A + (size_t)row * 256 + k0 + alk);
            int m = alm + half * 64;
            As[alk + 0][m] = av.x; As[alk + 1][m] = av.y;
            As[alk + 2][m] = av.z; As[alk + 3][m] = av.w;
        }
        float4 bv = *(const float4*)(B + (size_t)(k0 + blk) * 256 + bn + bln);
        *(float4*)&Bs[blk][bln] = bv;
        __syncthreads();
        #pragma unroll
        for (int kk = 0; kk < 16; ++kk) {
            float a[8], b[4];
            *(float4*)&a[0] = *(const float4*)&As[kk][tr * 8];
            *(float4*)&a[4] = *(const float4*)&As[kk][tr * 8 + 4];
            *(float4*)&b[0] = *(const float4*)&Bs[kk][tc * 4];
            #pragma unroll
            for (int i = 0; i < 8; ++i)
                #pragma unroll
                for (int j = 0; j < 4; ++j) acc[i][j] += a[i] * b[j];
        }
        __syncthreads();
    }
    #pragma unroll
    for (int i = 0; i < 8; ++i) {
        int row = bm + tr * 8 + i;
        if (row < NND) {
            int col = bn + tc * 4;
            float4 o;
            o.x = acc[i][0] + bias[col + 0];
            o.y = acc[i][1] + bias[col + 1];
            o.z = acc[i][2] + bias[col + 2];
            o.w = acc[i][3] + bias[col + 3];
            *(float4*)(C + (size_t)row * 256 + col) = o;
        }
    }
}

// ---------- per-node attention scores ----------
__global__ void k_scores(const float* Y, const float* attf, float* sD, float* sS) {
    int idx = blockIdx.x * blockDim.x + threadIdx.x;
    if (idx >= NND * HEADS) return;
    int n = idx >> 2, h = idx & 3;
    const float* xrow = Y + (size_t)n * 256 + 128 + h * 32;
    const float* ai = attf + h * 64;
    const float* aj = ai + 32;
    float si = 0.f, sj = 0.f;
    #pragma unroll
    for (int k = 0; k < 32; ++k) { float v = xrow[k]; si += v * ai[k]; sj += v * aj[k]; }
    sD[idx] = si; sS[idx] = sj;
}

// ---------- CSR build ----------
__global__ void k_count(const int* ei, int* counts) {
    int e = blockIdx.x * blockDim.x + threadIdx.x;
    if (e >= NE + NND) return;
    int d = (e < NE) ? ei[NE + e] : (e - NE);
    atomicAdd(&counts[d], 1);
}

__global__ void k_scan_blk(const int* counts, int* offsets, int* blksum) {
    int t = threadIdx.x, b = blockIdx.x;
    int i = b * 256 + t;
    int v = (i < NND) ? counts[i] : 0;
    int lane = t & 63, wv = t >> 6;
    int x = v;
    #pragma unroll
    for (int off = 1; off < 64; off <<= 1) {
        int y = __shfl_up(x, off);
        if (lane >= off) x += y;
    }
    __shared__ int wsum[4];
    if (lane == 63) wsum[wv] = x;
    __syncthreads();
    int add = 0;
    #pragma unroll
    for (int w = 0; w < 4; ++w) add += (w < wv) ? wsum[w] : 0;
    if (i < NND) offsets[i] = add + x - v;
    if (t == 255) blksum[b] = add + x;
}

__global__ void k_scan_top(const int* blksum, int* blkoff) {
    int t = threadIdx.x;
    int v = (t < SCAN_NB) ? blksum[t] : 0;
    int lane = t & 63, wv = t >> 6;
    int x = v;
    #pragma unroll
    for (int off = 1; off < 64; off <<= 1) {
        int y = __shfl_up(x, off);
        if (lane >= off) x += y;
    }
    __shared__ int ws2[2];
    if (lane == 63) ws2[wv] = x;
    __syncthreads();
    int add = (wv == 1) ? ws2[0] : 0;
    if (t < SCAN_NB) blkoff[t] = add + x - v;
}

__global__ void k_scan_add(const int* blkoff, int* offsets, int* cursor) {
    int i = blockIdx.x * 256 + threadIdx.x;
    if (i >= NND) return;
    int o = offsets[i] + blkoff[blockIdx.x];
    offsets[i] = o;
    cursor[i] = o;
}

__global__ void k_scatter(const int* ei, int* cursor, int* csr) {
    int e = blockIdx.x * blockDim.x + threadIdx.x;
    if (e >= NE + NND) return;
    int s, d;
    if (e < NE) { s = ei[e]; d = ei[NE + e]; } else { s = d = e - NE; }
    int pos = atomicAdd(&cursor[d], 1);
    csr[pos] = s;
}

// ---------- GAT aggregation: one wave per node ----------
__global__ __launch_bounds__(256) void k_aggr(const float* Y, const float* sD, const float* sS,
                                              const int* offsets, const int* counts, const int* csr,
                                              const float* bgat, float* xcg) {
    int wave = (blockIdx.x * blockDim.x + threadIdx.x) >> 6;
    int lane = threadIdx.x & 63;
    if (wave >= NND) return;
    int n = wave;
    int start = offsets[n], deg = counts[n];
    float4 sd = *(const float4*)(sD + (size_t)n * 4);
    float m0 = -1e30f, m1 = -1e30f, m2 = -1e30f, m3 = -1e30f;
    for (int e = lane; e < deg; e += 64) {
        int s = csr[start + e];
        float4 sj = *(const float4*)(sS + (size_t)s * 4);
        m0 = fmaxf(m0, lrelu(sd.x + sj.x));
        m1 = fmaxf(m1, lrelu(sd.y + sj.y));
        m2 = fmaxf(m2, lrelu(sd.z + sj.z));
        m3 = fmaxf(m3, lrelu(sd.w + sj.w));
    }
    m0 = redq_max64(m0); m1 = redq_max64(m1);
    m2 = redq_max64(m2); m3 = redq_max64(m3);
    float s0 = 0.f, s1 = 0.f, s2 = 0.f, s3 = 0.f;
    for (int e = lane; e < deg; e += 64) {
        int s = csr[start + e];
        float4 sj = *(const float4*)(sS + (size_t)s * 4);
        s0 += __expf(lrelu(sd.x + sj.x) - m0);
        s1 += __expf(lrelu(sd.y + sj.y) - m1);
        s2 += __expf(lrelu(sd.z + sj.z) - m2);
        s3 += __expf(lrelu(sd.w + sj.w) - m3);
    }
    s0 = redq_sum64(s0); s1 = redq_sum64(s1);
    s2 = redq_sum64(s2); s3 = redq_sum64(s3);
    float i0 = 1.0f / (s0 + 1e-16f), i1 = 1.0f / (s1 + 1e-16f);
    float i2 = 1.0f / (s2 + 1e-16f), i3 = 1.0f / (s3 + 1e-16f);
    float acc0 = 0.f, acc1 = 0.f;
    int hA = lane >> 5;
    for (int base = 0; base < deg; base += 64) {
        int cnt = min(64, deg - base);
        int sidx = 0; float w0 = 0.f, w1 = 0.f, w2 = 0.f, w3 = 0.f;
        if (base + lane < deg) {
            sidx = csr[start + base + lane];
            float4 sj = *(const float4*)(sS + (size_t)sidx * 4);
            w0 = __expf(lrelu(sd.x + sj.x) - m0) * i0;
            w1 = __expf(lrelu(sd.y + sj.y) - m1) * i1;
            w2 = __expf(lrelu(sd.z + sj.z) - m2) * i2;
            w3 = __expf(lrelu(sd.w + sj.w) - m3) * i3;
        }
        for (int j = 0; j < cnt; ++j) {
            int s2i = __builtin_amdgcn_readlane(sidx, j);
            float wa0 = __int_as_float(__builtin_amdgcn_readlane(__float_as_int(w0), j));
            float wa1 = __int_as_float(__builtin_amdgcn_readlane(__float_as_int(w1), j));
            float wb0 = __int_as_float(__builtin_amdgcn_readlane(__float_as_int(w2), j));
            float wb1 = __int_as_float(__builtin_amdgcn_readlane(__float_as_int(w3), j));
            float wA = hA ? wa1 : wa0;
            float wB = hA ? wb1 : wb0;
            const float* xrow = Y + (size_t)s2i * 256 + 128;
            acc0 += wA * xrow[lane];
            acc1 += wB * xrow[64 + lane];
        }
    }
    float r0 = acc0 + bgat[lane];
    float r1 = acc1 + bgat[64 + lane];
    xcg[(size_t)n * 128 + lane]      = r0 > 0.f ? r0 : 0.f;
    xcg[(size_t)n * 128 + 64 + lane] = r1 > 0.f ? r1 : 0.f;
}

// ---------- primary caps: u[n][128], one wave per node, barrier-free ----------
__global__ __launch_bounds__(256) void k_u(const float* Y, const float* xcg,
                                           const float* wpT, const float* bpf, float* uG) {
    int lane = threadIdx.x & 63;
    int gw = blockIdx.x * 4 + (threadIdx.x >> 6);
    int nwaves = gridDim.x * 4;
    int r = lane >> 3, oo = lane & 7;
    const float* wA = wpT + oo * 32;
    const float* wB = wpT + 256 + oo * 32;
    float bpA = bpf[oo], bpB = bpf[8 + oo];
    for (int n = gw; n < NND; n += nwaves) {
        const float* rowp = (r < 4) ? (xcg + (size_t)n * 128 + r * 32)
                                    : (Y + (size_t)n * 256 + (r - 4) * 32);
        float pcA = bpA, pcB = bpB;
        #pragma unroll
        for (int k4 = 0; k4 < 8; ++k4) {
            float4 xv = *(const float4*)(rowp + k4 * 4);
            float4 wa = *(const float4*)(wA + k4 * 4);
            float4 wb = *(const float4*)(wB + k4 * 4);
            xv.x = fmaxf(xv.x, 0.f); xv.y = fmaxf(xv.y, 0.f);
            xv.z = fmaxf(xv.z, 0.f); xv.w = fmaxf(xv.w, 0.f);
            pcA += xv.x * wa.x + xv.y * wa.y + xv.z * wa.z + xv.w * wa.w;
            pcB += xv.x * wb.x + xv.y * wb.y + xv.z * wb.z + xv.w * wb.w;
        }
        float sA = pcA * pcA, sB = pcB * pcB;
        sA += fdpp<0xB1>(sA); sA += fdpp<0x4E>(sA); sA += fswz<0x101F>(sA);
        sB += fdpp<0xB1>(sB); sB += fdpp<0x4E>(sB); sB += fswz<0x101F>(sB);
        float cA = sqrtf(sA) / (1.0f + sA);
        float cB = sqrtf(sB) / (1.0f + sB);
        uG[(size_t)n * 128 + lane]      = pcA * cA;
        uG[(size_t)n * 128 + 64 + lane] = pcB * cB;
    }
}

// ---------- dynamic routing: one wave per (node,c), 2-way node ILP, low register pressure ----------
// vs R8: rw is NOT hoisted (transient loads inside the p-loop; one load serves both
// nodes) and no e[] arrays (se/sl fused, p*vv recomputed) — persistent arrays are
// only p0/p1 + lg0/lg1 (~32 regs + scalars), so the 2-chain lockstep ILP runs
// without scratch spills (R8: 550 MB spill traffic at 64 VGPRs).
__global__ __launch_bounds__(256, 4) void k_route7(const float* uG, const float* rwT,
                                                   float* onorm, void* dout,
                                                   const unsigned int* graw) {
    int flag = dtype_flag(graw);
    int t = threadIdx.x;
    int lane = t & 63;
    int c = blockIdx.x >> 10;
    int chunk = blockIdx.x & 1023;
    int wv = t >> 6;
    int widx = chunk * 4 + wv;          // 0..4095
    const int nstep = 4096;
    int h = lane >> 5, o = lane & 31;
    int k = lane & 3;
    const float* rwp = rwT + ((size_t)(c * 32 + o) * 16 + h * 8) * 8;  // 64 contiguous floats
    float* outf = (float*)dout;
    __hip_bfloat16* outb = (__hip_bfloat16*)dout;
    for (int n0 = widx; n0 < NND; n0 += 2 * nstep) {
        int n1 = n0 + nstep;
        bool ok1 = (n1 < NND);
        const float* up0 = uG + (size_t)n0 * 128 + h * 64;
        const float* up1 = uG + (size_t)(ok1 ? n1 : n0) * 128 + h * 64;
        float p0[8], p1[8];
        #pragma unroll
        for (int j = 0; j < 8; ++j) {
            float4 ra = *(const float4*)(rwp + j * 8);
            float4 rb = *(const float4*)(rwp + j * 8 + 4);
            float4 a0 = *(const float4*)(up0 + j * 8);
            float4 b0 = *(const float4*)(up0 + j * 8 + 4);
            float4 a1 = *(const float4*)(up1 + j * 8);
            float4 b1 = *(const float4*)(up1 + j * 8 + 4);
            p0[j] = a0.x*ra.x + a0.y*ra.y + a0.z*ra.z + a0.w*ra.w
                  + b0.x*rb.x + b0.y*rb.y + b0.z*rb.z + b0.w*rb.w;
            p1[j] = a1.x*ra.x + a1.y*ra.y + a1.z*ra.z + a1.w*ra.w
                  + b1.x*rb.x + b1.y*rb.y + b1.z*rb.z + b1.w*rb.w;
        }
        // ---- iter 1: probs = 1/16 exactly ----
        float tl0 = p0[0]+p0[1]+p0[2]+p0[3]+p0[4]+p0[5]+p0[6]+p0[7];
        float tl1 = p1[0]+p1[1]+p1[2]+p1[3]+p1[4]+p1[5]+p1[6]+p1[7];
        float s0 = (tl0 + __shfl_xor(tl0, 32)) * 0.0625f;
        float s1 = (tl1 + __shfl_xor(tl1, 32)) * 0.0625f;
        float sq0 = s0 * s0, sq1 = s1 * s1;
        redq2(sq0, sq1);
        float v0 = s0 * (sqrtf(sq0) / (1.0f + sq0));
        float v1 = s1 * (sqrtf(sq1) / (1.0f + sq1));
        float lg0[8], lg1[8];
        {
            float d0[8], d1[8];
            #pragma unroll
            for (int j = 0; j < 8; ++j) { d0[j] = p0[j] * v0; d1[j] = p1[j] * v1; }
            dreduce2(d0, d1, k, lg0, lg1);
        }
        // ---- iters 2,3 ----
        float sq3_0 = 0.f, v3_0 = 0.f, sq3_1 = 0.f, v3_1 = 0.f;
        #pragma unroll
        for (int it = 0; it < 2; ++it) {
            float mx0 = lg0[0], mx1 = lg1[0];
            #pragma unroll
            for (int j = 1; j < 8; ++j) { mx0 = fmaxf(mx0, lg0[j]); mx1 = fmaxf(mx1, lg1[j]); }
            mx0 = fmaxf(mx0, __shfl_xor(mx0, 32));
            mx1 = fmaxf(mx1, __shfl_xor(mx1, 32));
            float se0 = 0.f, sl0 = 0.f, se1 = 0.f, sl1 = 0.f;
            #pragma unroll
            for (int j = 0; j < 8; ++j) {
                float e0 = __expf(lg0[j] - mx0); se0 += e0; sl0 += e0 * p0[j];
                float e1 = __expf(lg1[j] - mx1); se1 += e1; sl1 += e1 * p1[j];
            }
            se0 += __shfl_xor(se0, 32);
            se1 += __shfl_xor(se1, 32);
            sl0 /= se0; sl1 /= se1;
            float ss0 = sl0 + __shfl_xor(sl0, 32);
            float ss1 = sl1 + __shfl_xor(sl1, 32);
            float q0 = ss0 * ss0, q1 = ss1 * ss1;
            redq2(q0, q1);
            float vv0 = ss0 * (sqrtf(q0) / (1.0f + q0));
            float vv1 = ss1 * (sqrtf(q1) / (1.0f + q1));
            if (it == 0) {
                float d0[8], d1[8], u0a[8], u1a[8];
                #pragma unroll
                for (int j = 0; j < 8; ++j) { d0[j] = p0[j] * vv0; d1[j] = p1[j] * vv1; }
                dreduce2(d0, d1, k, u0a, u1a);
                #pragma unroll
                for (int j = 0; j < 8; ++j) { lg0[j] += u0a[j]; lg1[j] += u1a[j]; }
            } else { v3_0 = vv0; sq3_0 = q0; v3_1 = vv1; sq3_1 = q1; }
        }
        // ---- output ----
        if (lane < 32) {
            size_t f0 = (size_t)OUT_FEAT_IDX + (size_t)n0 * 192 + c * 32 + o;
            if (flag) outb[f0] = __float2bfloat16(v3_0); else outf[f0] = v3_0;
            if (ok1) {
                size_t f1 = (size_t)OUT_FEAT_IDX + (size_t)n1 * 192 + c * 32 + o;
                if (flag) outb[f1] = __float2bfloat16(v3_1); else outf[f1] = v3_1;
            }
            if (lane == 0) {
                float norm0 = sq3_0 / (1.0f + sq3_0);
                onorm[n0 * 6 + c] = norm0;
                size_t o0i = (size_t)n0 * 6 + c;
                if (flag) outb[o0i] = __float2bfloat16(norm0); else outf[o0i] = norm0;
                if (ok1) {
                    float norm1 = sq3_1 / (1.0f + sq3_1);
                    onorm[n1 * 6 + c] = norm1;
                    size_t o1i = (size_t)n1 * 6 + c;
                    if (flag) outb[o1i] = __float2bfloat16(norm1); else outf[o1i] = norm1;
                }
            }
        }
    }
}

// ---------- loss ----------
__global__ void k_loss(const float* onorm, const int* y, float* acc) {
    float l = 0.f;
    for (int n = blockIdx.x * blockDim.x + threadIdx.x; n < NND; n += gridDim.x * blockDim.x) {
        const float* v = onorm + n * 6;
        float m = v[0];
        #pragma unroll
        for (int cc = 1; cc < 6; ++cc) m = fmaxf(m, v[cc]);
        float s = 0.f;
        #pragma unroll
        for (int cc = 0; cc < 6; ++cc) s += expf(v[cc] - m);
        l += m + logf(s) - v[y[n]];
    }
    __shared__ float red[256];
    red[threadIdx.x] = l;
    __syncthreads();
    for (int s = 128; s > 0; s >>= 1) { if (threadIdx.x < s) red[threadIdx.x] += red[threadIdx.x + s]; __syncthreads(); }
    if (threadIdx.x == 0) atomicAdd(acc, red[0]);
}

__global__ void k_loss_fin(const float* acc, void* dout, const unsigned int* graw) {
    float v = acc[0] / (float)NND;
    if (dtype_flag(graw)) ((__hip_bfloat16*)dout)[OUT_LOSS_IDX] = __float2bfloat16(v);
    else                  ((float*)dout)[OUT_LOSS_IDX] = v;
}

extern "C" void kernel_launch(void* const* d_in, const int* in_sizes, int n_in,
                              void* d_out, int out_size, void* d_ws, size_t ws_size,
                              hipStream_t stream) {
    (void)in_sizes; (void)n_in; (void)out_size; (void)ws_size;
    float* ws = (float*)d_ws;
    int*  wsi = (int*)d_ws;
    const int* ei = (const int*)d_in[11];
    const int* y  = (const int*)d_in[12];
    const unsigned int* graw = (const unsigned int*)d_in[1];

    hipMemsetAsync(d_ws, 0, (size_t)WS_ZERO_ELEMS * 4, stream);

    k_convert<<<2048, 256, 0, stream>>>(d_in[0], ws + WS_XF, NND * FD, graw);
    k_convert_params<<<(91664 + 255) / 256, 256, 0, stream>>>(
        d_in[1], d_in[2], d_in[3], d_in[4], d_in[5], d_in[6], d_in[7], d_in[8], d_in[9], d_in[10],
        ws + WS_GAMMA);

    k_bn_stats<<<240, 256, 0, stream>>>(ws + WS_XF, ws + WS_BNSUM, ws + WS_BNSQ);
    k_bn_final<<<1, 256, 0, stream>>>(ws + WS_BNSUM, ws + WS_BNSQ, ws + WS_GAMMA, ws + WS_BETA,
                                      ws + WS_SCALE, ws + WS_SHIFT);
    k_fold<<<256, 256, 0, stream>>>(ws + WS_WLIN, ws + WS_WGAT, ws + WS_BLIN,
                                    ws + WS_SCALE, ws + WS_SHIFT, ws + WS_WC, ws + WS_BC);

    k_gemm<<<dim3((NND + 127) / 128, 4), 256, 0, stream>>>(ws + WS_XF, ws + WS_WC, ws + WS_BC, ws + WS_Y);

    k_scores<<<(NND * HEADS + 255) / 256, 256, 0, stream>>>(ws + WS_Y, ws + WS_ATT, ws + WS_SD, ws + WS_SS);

    k_count<<<(NE + NND + 255) / 256, 256, 0, stream>>>(ei, wsi + WS_COUNTS);
    k_scan_blk<<<SCAN_NB, 256, 0, stream>>>(wsi + WS_COUNTS, wsi + WS_OFFSETS, wsi + WS_BLKSUM);
    k_scan_top<<<1, 128, 0, stream>>>(wsi + WS_BLKSUM, wsi + WS_BLKOFF);
    k_scan_add<<<SCAN_NB, 256, 0, stream>>>(wsi + WS_BLKOFF, wsi + WS_OFFSETS, wsi + WS_CURSOR);
    k_scatter<<<(NE + NND + 255) / 256, 256, 0, stream>>>(ei, wsi + WS_CURSOR, wsi + WS_CSR);

    k_aggr<<<(NND + 3) / 4, 256, 0, stream>>>(ws + WS_Y, ws + WS_SD, ws + WS_SS,
                                              wsi + WS_OFFSETS, wsi + WS_COUNTS, wsi + WS_CSR,
                                              ws + WS_BGAT, ws + WS_XCG);

    // rwT/wpT overlay the sD region — safe only after k_aggr's last read of sD
    k_prep<<<(24576 + 512 + 255) / 256, 256, 0, stream>>>(ws + WS_RW, ws + WS_WP,
                                                          ws + WS_RWT, ws + WS_WPT);

    k_u<<<512, 256, 0, stream>>>(ws + WS_Y, ws + WS_XCG, ws + WS_WPT, ws + WS_BP, ws + WS_U);
    k_route7<<<6144, 256, 0, stream>>>(ws + WS_U, ws + WS_RWT, ws + WS_ONORM, d_out, graw);

    k_loss<<<118, 256, 0, stream>>>(ws + WS_ONORM, y, ws + WS_LOSS);
    k_loss_fin<<<1, 1, 0, stream>>>(ws + WS_LOSS, d_out, graw);
}